// Round 4
// baseline (338.196 us; speedup 1.0000x reference)
//
#include <hip/hip_runtime.h>
#include <math.h>

namespace {

constexpr int H = 2048;
constexpr int W = 2048;
constexpr int ROWS = 4;                           // rows per block (4x256 tile)
constexpr float TANH_C  = 1.1486328125f;
constexpr float DEG2RAD = 0.017453292519943295f;  // == np.float32(pi/180)
constexpr float RT2H    = 0.70710678118654752f;   // sqrt(2)/2
constexpr float BAND    = 2.5e-4f;                // fast-path err ~4e-5 << BAND

// out layout: [0,HW) p_ignite, [HW,2HW) new_burning (0/1), [2HW,3HW) new_burned
__global__ __launch_bounds__(256, 2) void wildfire_step(
    const float* __restrict__ p_veg,  const float* __restrict__ p_den,
    const float* __restrict__ wind_v, const float* __restrict__ wind_d,
    const float* __restrict__ slope,
    const float* __restrict__ s_a,  const float* __restrict__ s_ph,
    const float* __restrict__ s_c1, const float* __restrict__ s_c2,
    const float* __restrict__ s_pc,
    const float* __restrict__ rand_ig, const float* __restrict__ rand_co,
    const int* __restrict__ burning, const int* __restrict__ burned,
    float* __restrict__ out)
{
    __shared__ float sb[ROWS + 2][260];   // burning halo rows i0-1..i0+ROWS
    const int t  = (int)threadIdx.x;
    const int i0 = (int)blockIdx.y * ROWS;
    const int j0 = (int)blockIdx.x * 256;
    const int j  = j0 + t;

    // ---------- phase A: issue ALL global loads up front ----------
    // halo loads into regs (LDS write deferred so per-cell loads issue first-class)
    float ha[ROWS + 2], hbx[ROWS + 2];
    #pragma unroll
    for (int r = 0; r < ROWS + 2; ++r) {
        const int ii = i0 - 1 + r;
        const int jj = j0 - 1 + t;               // max 2046 < W
        float v = 0.f;
        if (ii >= 0 && ii < H && jj >= 0) v = burning[ii * W + jj] ? 1.f : 0.f;
        ha[r] = v;
        float v2 = 0.f;
        if (t < 2) {
            const int jj2 = j0 + 255 + t;        // halo cols 256,257
            if (ii >= 0 && ii < H && jj2 < W) v2 = burning[ii * W + jj2] ? 1.f : 0.f;
        }
        hbx[r] = v2;
    }

    // per-cell inputs for all 4 rows, unconditional
    float pv[ROWS], pd[ROWS], wvl[ROWS], wdl[ROWS], rig[ROWS], rco[ROWS];
    int   bd[ROWS];
    float sl[ROWS][9];
    #pragma unroll
    for (int r = 0; r < ROWS; ++r) {
        const int idx = (i0 + r) * W + j;
        pv[r]  = p_veg[idx];
        pd[r]  = p_den[idx];
        wvl[r] = wind_v[idx];
        wdl[r] = wind_d[idx];
        rig[r] = rand_ig[idx];
        rco[r] = rand_co[idx];
        bd[r]  = burned[idx];
        __builtin_memcpy(sl[r], slope + (size_t)idx * 9, 9 * sizeof(float));
    }

    const float a      = s_a[0];
    const float p_h    = s_ph[0];
    const float c1     = s_c1[0];
    const float c2     = s_c2[0];
    const float p_cont = s_pc[0];

    // halo -> LDS, one barrier
    #pragma unroll
    for (int r = 0; r < ROWS + 2; ++r) {
        sb[r][t] = ha[r];
        if (t < 2) sb[r][256 + t] = hbx[r];
    }
    __syncthreads();

    float wA[ROWS + 2], wB[ROWS + 2], wC[ROWS + 2];
    #pragma unroll
    for (int r = 0; r < ROWS + 2; ++r) {
        wA[r] = sb[r][t]; wB[r] = sb[r][t + 1]; wC[r] = sb[r][t + 2];
    }

    // ---------- phase B: compute + store, 4 independent rows ----------
    #pragma unroll
    for (int r = 0; r < ROWS; ++r) {
        const float b0 = wA[r],     b1 = wB[r],     b2 = wC[r];
        const float b3 = wA[r + 1], bcn = wB[r + 1], b5 = wC[r + 1];
        const float b6 = wA[r + 2], b7 = wB[r + 2], b8 = wC[r + 2];

        const int   idx        = (i0 + r) * W + j;
        const bool  is_burning = (bcn != 0.f);
        const float any_n = b0 + b1 + b2 + b3 + b5 + b6 + b7 + b8; // integer-valued

        float p_ig   = 0.f;
        bool  new_ig = false;

        if (__any(any_n != 0.f)) {
            const float wr  = wdl[r] * DEG2RAD;
            const float cw  = __cosf(wr);
            const float sw  = __sinf(wr);
            const float ew  = __expf(c1 * wvl[r]);
            const float cvw = c2 * wvl[r];
            const float asl = a * DEG2RAD;
            const float p_base = (p_h * (1.f + pv[r])) * (1.f + pd[r]);
            const float Cz2 = 2.f * (TANH_C * (p_base * ew));

            // 1 - tanh(z_k)*b_k = b_k ? 2/(E_k+1) : 1,  E_k = exp(Cz2*exp(u_k))
#define NB(K, b, CK, SK, si)                                                  \
            const float ct##K = fmaf(cw, (CK), sw * (SK));                    \
            const float eu##K = __expf(fmaf(cvw, ct##K - 1.f, asl * sl[r][si])); \
            const float E##K  = __expf(Cz2 * eu##K);                          \
            const float d##K  = fmaf((b), E##K, 1.f);

            NB(0, b0,  RT2H, -RT2H, 0)   // 315
            NB(1, b1,  0.f,  -1.f,  1)   // 270
            NB(2, b2, -RT2H, -RT2H, 2)   // 225
            NB(3, b3,  1.f,   0.f,  3)   //   0
            NB(5, b5, -1.f,   0.f,  5)   // 180
            NB(6, b6,  RT2H,  RT2H, 6)   //  45
            NB(7, b7,  0.f,   1.f,  7)   //  90
            NB(8, b8, -RT2H,  RT2H, 8)   // 135
#undef NB
            const float den = ((d0 * d1) * (d2 * d3)) * ((d5 * d6) * (d7 * d8));
            const float num = (float)(1 << (int)any_n); // 2^m exact
            p_ig = 1.f - num * __builtin_amdgcn_rcpf(den);

            new_ig = (!is_burning) && (bd[r] == 0) && (rig[r] < p_ig);

            // precise recheck where the bool could flip (~60 cells / grid)
            const bool need = (any_n != 0.f) && (fabsf(rig[r] - p_ig) < BAND);
            if (__any((int)need)) {
                if (need) {
                    const float ewp = expf(c1 * wvl[r]);
                    float prod = 1.f;
#define NBP(b, dirdeg, si)                                                    \
                    if ((b) != 0.f) {                                         \
                        const float th = (wdl[r] - (dirdeg)) * DEG2RAD;       \
                        const float pw = ewp * expf(cvw * (cosf(th) - 1.f));  \
                        const float ps = expf((a * sl[r][si]) * DEG2RAD);     \
                        const float pp = tanhf(TANH_C * ((p_base * pw) * ps)); \
                        prod *= 1.f - pp * (b);                               \
                    }
                    NBP(b0, 315.f, 0)
                    NBP(b1, 270.f, 1)
                    NBP(b2, 225.f, 2)
                    NBP(b3,   0.f, 3)
                    NBP(b5, 180.f, 5)
                    NBP(b6,  45.f, 6)
                    NBP(b7,  90.f, 7)
                    NBP(b8, 135.f, 8)
#undef NBP
                    p_ig   = 1.f - prod;
                    new_ig = (!is_burning) && (bd[r] == 0) && (rig[r] < p_ig);
                }
            }
        }

        const bool keep = is_burning && (rco[r] < p_cont);
        const bool nb   = new_ig || keep;
        const bool nd   = (bd[r] != 0) || (is_burning && !keep);

        out[idx]             = p_ig;
        out[H * W + idx]     = nb ? 1.f : 0.f;
        out[2 * H * W + idx] = nd ? 1.f : 0.f;
    }
}

} // namespace

extern "C" void kernel_launch(void* const* d_in, const int* in_sizes, int n_in,
                              void* d_out, int out_size, void* d_ws, size_t ws_size,
                              hipStream_t stream)
{
    (void)in_sizes; (void)n_in; (void)out_size; (void)d_ws; (void)ws_size;
    dim3 grid(W / 256, H / ROWS, 1);
    dim3 block(256, 1, 1);
    hipLaunchKernelGGL(wildfire_step, grid, block, 0, stream,
        (const float*)d_in[0],  (const float*)d_in[1],
        (const float*)d_in[2],  (const float*)d_in[3],
        (const float*)d_in[4],
        (const float*)d_in[5],  (const float*)d_in[6],
        (const float*)d_in[7],  (const float*)d_in[8],
        (const float*)d_in[9],
        (const float*)d_in[10], (const float*)d_in[11],
        (const int*)d_in[12],   (const int*)d_in[13],
        (float*)d_out);
}

// Round 5
// 331.870 us; speedup vs baseline: 1.0191x; 1.0191x over previous
//
#include <hip/hip_runtime.h>
#include <math.h>

namespace {

constexpr int H = 2048;
constexpr int W = 2048;
constexpr float TANH_C  = 1.1486328125f;
constexpr float DEG2RAD = 0.017453292519943295f; // == np.float32(pi/180)
constexpr float RT2H    = 0.70710678118654752f;  // sqrt(2)/2
constexpr float BAND    = 2.5e-4f;               // fast-path err ~4e-5 << BAND

// out layout: [0,HW) p_ignite, [HW,2HW) new_burning (0/1), [2HW,3HW) new_burned
__global__ __launch_bounds__(256) void wildfire_step(
    const float* __restrict__ p_veg,  const float* __restrict__ p_den,
    const float* __restrict__ wind_v, const float* __restrict__ wind_d,
    const float* __restrict__ slope,
    const float* __restrict__ s_a,  const float* __restrict__ s_ph,
    const float* __restrict__ s_c1, const float* __restrict__ s_c2,
    const float* __restrict__ s_pc,
    const float* __restrict__ rand_ig, const float* __restrict__ rand_co,
    const int* __restrict__ burning, const int* __restrict__ burned,
    float* __restrict__ out)
{
    __shared__ float sb[3][260];                    // burning halo
    __shared__ __align__(16) float ssl[256 * 9];    // slope tile, 9216 B, dense-staged
    const int t  = (int)threadIdx.x;
    const int i  = (int)blockIdx.y;
    const int j0 = (int)blockIdx.x * 256;
    const int j  = j0 + t;
    const int idx = i * W + j;

    // ---- dense float4 staging of the tile's contiguous slope block ----
    // byte offset (i*W+j0)*36 is 16B-aligned (j0 % 256 == 0 -> offset % 9216 == 0)
    {
        const float4* sg  = reinterpret_cast<const float4*>(slope + (size_t)(i * W + j0) * 9);
        float4*       sl4 = reinterpret_cast<float4*>(ssl);
        sl4[t]       = sg[t];
        sl4[256 + t] = sg[256 + t];
        if (t < 64) sl4[512 + t] = sg[512 + t];     // 576 float4s total
    }

    // ---- burning halo staging (dword, dense) ----
    for (int r = 0; r < 3; ++r) {
        const int ii = i + r - 1;
        for (int c = t; c < 258; c += 256) {
            const int jj = j0 - 1 + c;
            float v = 0.f;
            if (ii >= 0 && ii < H && jj >= 0 && jj < W)
                v = burning[ii * W + jj] ? 1.f : 0.f;
            sb[r][c] = v;
        }
    }

    // ---- per-cell loads (independent, overlap staging latency) ----
    const float pv  = p_veg[idx];
    const float pd  = p_den[idx];
    const float wv  = wind_v[idx];
    const float wd  = wind_d[idx];
    const float rig = rand_ig[idx];
    const float rco = rand_co[idx];
    const int   wb  = burned[idx];

    const float a      = s_a[0];
    const float p_h    = s_ph[0];
    const float c1     = s_c1[0];
    const float c2     = s_c2[0];
    const float p_cont = s_pc[0];

    __syncthreads();

    const float b0 = sb[0][t], b1 = sb[0][t+1], b2 = sb[0][t+2];
    const float b3 = sb[1][t], bc = sb[1][t+1], b5 = sb[1][t+2];
    const float b6 = sb[2][t], b7 = sb[2][t+1], b8 = sb[2][t+2];

    const bool  is_burning = (bc != 0.f);
    const float any_n = b0 + b1 + b2 + b3 + b5 + b6 + b7 + b8; // integer-valued

    const float* sl = ssl + t * 9;   // stride 9 words: conflict-free mod 32 banks

    float p_ignite    = 0.f;
    bool  new_ignited = false;

    if (__any(any_n != 0.f)) {              // wave-uniform heavy path (~86% of waves)
        const float wr  = wd * DEG2RAD;
        const float cw  = __cosf(wr);
        const float sw  = __sinf(wr);
        const float ew  = __expf(c1 * wv);
        const float cvw = c2 * wv;
        const float asl = a * DEG2RAD;
        const float p_base = (p_h * (1.f + pv)) * (1.f + pd);
        const float Cz2 = 2.f * (TANH_C * (p_base * ew));

        // 1 - tanh(z_k)*b_k = b_k ? 2/(E_k+1) : 1,  E_k = exp(Cz2*exp(u_k))
        // => p_ignite = 1 - 2^m / prod(fma(b_k, E_k, 1))
#define NB(K, b, CK, SK, si)                                                \
        const float ct##K = fmaf(cw, (CK), sw * (SK));                      \
        const float eu##K = __expf(fmaf(cvw, ct##K - 1.f, asl * sl[si]));   \
        const float E##K  = __expf(Cz2 * eu##K);                            \
        const float d##K  = fmaf((b), E##K, 1.f);

        NB(0, b0,  RT2H, -RT2H, 0)   // 315
        NB(1, b1,  0.f,  -1.f,  1)   // 270
        NB(2, b2, -RT2H, -RT2H, 2)   // 225
        NB(3, b3,  1.f,   0.f,  3)   //   0
        NB(5, b5, -1.f,   0.f,  5)   // 180
        NB(6, b6,  RT2H,  RT2H, 6)   //  45
        NB(7, b7,  0.f,   1.f,  7)   //  90
        NB(8, b8, -RT2H,  RT2H, 8)   // 135
#undef NB
        const float den = ((d0 * d1) * (d2 * d3)) * ((d5 * d6) * (d7 * d8));
        const float num = (float)(1 << (int)any_n);   // 2^m exactly
        p_ignite = 1.f - num * __builtin_amdgcn_rcpf(den);

        new_ignited = (!is_burning) && (wb == 0) && (rig < p_ignite);

        // ---- precise recheck where the bool could flip (~60 cells/grid) ----
        const bool need = (any_n != 0.f) && (fabsf(rig - p_ignite) < BAND);
        if (__any((int)need)) {
            if (need) {
                const float ewp = expf(c1 * wv);
                float prod = 1.f;
#define NBP(b, dirdeg, si)                                                  \
                if ((b) != 0.f) {                                           \
                    const float th = (wd - (dirdeg)) * DEG2RAD;             \
                    const float pw = ewp * expf(cvw * (cosf(th) - 1.f));    \
                    const float ps = expf((a * sl[si]) * DEG2RAD);          \
                    const float pp = tanhf(TANH_C * ((p_base * pw) * ps));  \
                    prod *= 1.f - pp * (b);                                 \
                }
                NBP(b0, 315.f, 0)
                NBP(b1, 270.f, 1)
                NBP(b2, 225.f, 2)
                NBP(b3,   0.f, 3)
                NBP(b5, 180.f, 5)
                NBP(b6,  45.f, 6)
                NBP(b7,  90.f, 7)
                NBP(b8, 135.f, 8)
#undef NBP
                p_ignite    = 1.f - prod;
                new_ignited = (!is_burning) && (wb == 0) && (rig < p_ignite);
            }
        }
    }

    const bool keep = is_burning && (rco < p_cont);
    const bool nb   = new_ignited || keep;
    const bool nd   = (wb != 0) || (is_burning && !keep);

    out[idx]             = p_ignite;
    out[H * W + idx]     = nb ? 1.f : 0.f;
    out[2 * H * W + idx] = nd ? 1.f : 0.f;
}

} // namespace

extern "C" void kernel_launch(void* const* d_in, const int* in_sizes, int n_in,
                              void* d_out, int out_size, void* d_ws, size_t ws_size,
                              hipStream_t stream)
{
    (void)in_sizes; (void)n_in; (void)out_size; (void)d_ws; (void)ws_size;
    dim3 grid(W / 256, H, 1);
    dim3 block(256, 1, 1);
    hipLaunchKernelGGL(wildfire_step, grid, block, 0, stream,
        (const float*)d_in[0],  (const float*)d_in[1],
        (const float*)d_in[2],  (const float*)d_in[3],
        (const float*)d_in[4],
        (const float*)d_in[5],  (const float*)d_in[6],
        (const float*)d_in[7],  (const float*)d_in[8],
        (const float*)d_in[9],
        (const float*)d_in[10], (const float*)d_in[11],
        (const int*)d_in[12],   (const int*)d_in[13],
        (float*)d_out);
}